// Round 2
// baseline (122.008 us; speedup 1.0000x reference)
//
#include <hip/hip_runtime.h>

#define N_ATOMS 250000
#define NR 8

// Grid: x = atoms/256, y = t (0..7). One thread computes all 36 tril (r,s)
// outputs for its (atom, t). lane = atom -> coalesced stores.
__global__ __launch_bounds__(256) void moment_contr_kernel(
    const float* __restrict__ m1,   // [A, 8, 3]
    const float* __restrict__ m2,   // [A, 8, 3, 3]
    float* __restrict__ out)        // flat: out[p*2000000 + t*250000 + a]
{
    const int a = blockIdx.x * blockDim.x + threadIdx.x;
    const int t = blockIdx.y;
    if (a >= N_ATOMS) return;

    // ---- m1[a]: 24 floats via 6x float4 (96 B per lane, 16B-aligned) ----
    float m1v[24];
    {
        const float4* p = reinterpret_cast<const float4*>(m1 + (size_t)a * 24);
        #pragma unroll
        for (int k = 0; k < 6; ++k) {
            float4 v = p[k];
            m1v[4*k+0] = v.x; m1v[4*k+1] = v.y;
            m1v[4*k+2] = v.z; m1v[4*k+3] = v.w;
        }
    }

    // ---- m2[a, t]: 9 floats (only 4B-aligned -> scalar dword loads) ----
    float m2t[9];
    {
        const float* p = m2 + (size_t)a * 72 + (size_t)t * 9;
        #pragma unroll
        for (int k = 0; k < 9; ++k) m2t[k] = p[k];
    }

    // B[s][i] = sum_j m1[s,j] * m2[t,i,j]
    float B[24];
    #pragma unroll
    for (int s = 0; s < NR; ++s) {
        #pragma unroll
        for (int i = 0; i < 3; ++i) {
            B[s*3+i] = m1v[s*3+0] * m2t[i*3+0]
                     + m1v[s*3+1] * m2t[i*3+1]
                     + m1v[s*3+2] * m2t[i*3+2];
        }
    }

    // contr[r,s,t] = sum_i m1[r,i] * B[s,i]; p = r*(r+1)/2 + s matches
    // np.tril_indices(8) order. Non-temporal: 288 MB stream, keep L2 for m1.
    float* outa = out + (size_t)t * N_ATOMS + a;
    #pragma unroll
    for (int r = 0; r < NR; ++r) {
        #pragma unroll
        for (int s = 0; s <= r; ++s) {
            const int p = r*(r+1)/2 + s;
            float v = m1v[r*3+0] * B[s*3+0]
                    + m1v[r*3+1] * B[s*3+1]
                    + m1v[r*3+2] * B[s*3+2];
            __builtin_nontemporal_store(v, outa + (size_t)p * (NR * N_ATOMS));
        }
    }
}

extern "C" void kernel_launch(void* const* d_in, const int* in_sizes, int n_in,
                              void* d_out, int out_size, void* d_ws, size_t ws_size,
                              hipStream_t stream) {
    const float* m1 = (const float*)d_in[0];
    const float* m2 = (const float*)d_in[1];
    float* out = (float*)d_out;

    const int block = 256;
    const int gx = (N_ATOMS + block - 1) / block;
    hipLaunchKernelGGL(moment_contr_kernel, dim3(gx, NR), dim3(block), 0, stream,
                       m1, m2, out);
}

// Round 3
// 110.128 us; speedup vs baseline: 1.1079x; 1.1079x over previous
//
#include <hip/hip_runtime.h>

#define N_ATOMS 250000
#define NR 8

__global__ __launch_bounds__(256) void moment_contr_kernel(
    const float* __restrict__ m1,   // [A, 8, 3]
    const float* __restrict__ m2,   // [A, 8, 3, 3]
    float* __restrict__ out)        // flat: out[p*2000000 + t*250000 + a]
{
    const int a = blockIdx.x * blockDim.x + threadIdx.x;
    if (a >= N_ATOMS) return;

    // ---- load m1[a]: 24 floats via 6x float4 (96 B contiguous per lane) ----
    float m1v[24];
    {
        const float4* p = reinterpret_cast<const float4*>(m1 + (size_t)a * 24);
        #pragma unroll
        for (int k = 0; k < 6; ++k) {
            float4 v = p[k];
            m1v[4*k+0] = v.x; m1v[4*k+1] = v.y;
            m1v[4*k+2] = v.z; m1v[4*k+3] = v.w;
        }
    }

    // ---- load m2[a]: 72 floats via 18x float4 (288 B contiguous per lane) ----
    float m2v[72];
    {
        const float4* p = reinterpret_cast<const float4*>(m2 + (size_t)a * 72);
        #pragma unroll
        for (int k = 0; k < 18; ++k) {
            float4 v = p[k];
            m2v[4*k+0] = v.x; m2v[4*k+1] = v.y;
            m2v[4*k+2] = v.z; m2v[4*k+3] = v.w;
        }
    }

    float* outa = out + a;

    // FULLY unrolled t-loop: every index below is compile-time constant, so
    // m1v/m2v/B all stay in VGPRs (rule #20 — runtime-indexed register arrays
    // get demoted to scratch).
    #pragma unroll
    for (int t = 0; t < NR; ++t) {
        // B[s][i] = sum_j m1[s,j] * m2[t,i,j]
        float B[24];
        #pragma unroll
        for (int s = 0; s < NR; ++s) {
            #pragma unroll
            for (int i = 0; i < 3; ++i) {
                B[s*3+i] = m1v[s*3+0] * m2v[t*9 + i*3 + 0]
                         + m1v[s*3+1] * m2v[t*9 + i*3 + 1]
                         + m1v[s*3+2] * m2v[t*9 + i*3 + 2];
            }
        }
        // contr[r,s,t] = sum_i m1[r,i] * B[s,i]; p = r*(r+1)/2 + s matches
        // np.tril_indices(8) order.
        #pragma unroll
        for (int r = 0; r < NR; ++r) {
            #pragma unroll
            for (int s = 0; s <= r; ++s) {
                const int p = r*(r+1)/2 + s;
                float v = m1v[r*3+0] * B[s*3+0]
                        + m1v[r*3+1] * B[s*3+1]
                        + m1v[r*3+2] * B[s*3+2];
                outa[(size_t)p * (NR * N_ATOMS) + (size_t)t * N_ATOMS] = v;
            }
        }
    }
}

extern "C" void kernel_launch(void* const* d_in, const int* in_sizes, int n_in,
                              void* d_out, int out_size, void* d_ws, size_t ws_size,
                              hipStream_t stream) {
    const float* m1 = (const float*)d_in[0];
    const float* m2 = (const float*)d_in[1];
    float* out = (float*)d_out;

    const int block = 256;
    const int grid = (N_ATOMS + block - 1) / block;
    hipLaunchKernelGGL(moment_contr_kernel, dim3(grid), dim3(block), 0, stream,
                       m1, m2, out);
}

// Round 4
// 104.937 us; speedup vs baseline: 1.1627x; 1.0495x over previous
//
#include <hip/hip_runtime.h>

#define N_ATOMS 250000
#define NR 8
#define BLK 512          // threads per block == atoms per block
#define NP 36            // tril pairs

// Grid: 489 blocks of 512 threads, one atom per thread.
// t-outer loop; outputs staged in LDS per t, then written out cooperatively
// as float4 so each wave-store covers 1 KB contiguous and each (p,t) region
// receives a 2 KB sequential run per block.
__global__ __launch_bounds__(BLK, 4) void moment_contr_kernel(
    const float* __restrict__ m1,   // [A, 8, 3]
    const float* __restrict__ m2,   // [A, 8, 3, 3]
    float* __restrict__ out)        // out[p*2000000 + t*250000 + a]
{
    __shared__ float sbuf[NP][BLK];  // 36*512*4 = 72 KB -> 2 blocks/CU

    const int tid = threadIdx.x;
    const long long block_base = (long long)blockIdx.x * BLK;
    const long long a = block_base + tid;
    const bool live = (a < N_ATOMS);

    // ---- m1[a]: 24 floats, kept in VGPRs for all 8 t-passes ----
    float m1v[24];
    if (live) {
        const float4* p = reinterpret_cast<const float4*>(m1 + (size_t)a * 24);
        #pragma unroll
        for (int k = 0; k < 6; ++k) {
            float4 v = p[k];
            m1v[4*k+0] = v.x; m1v[4*k+1] = v.y;
            m1v[4*k+2] = v.z; m1v[4*k+3] = v.w;
        }
    } else {
        #pragma unroll
        for (int k = 0; k < 24; ++k) m1v[k] = 0.f;
    }

    // t-loop rolled: all register arrays below are statically indexed within
    // one iteration, so nothing spills; code stays compact.
    for (int t = 0; t < NR; ++t) {
        // ---- m2[a,t]: 9 floats (36 B per lane; repeat passes hit L2/L3) ----
        float m2t[9];
        if (live) {
            const float* p = m2 + (size_t)a * 72 + (size_t)t * 9;
            #pragma unroll
            for (int k = 0; k < 9; ++k) m2t[k] = p[k];
        } else {
            #pragma unroll
            for (int k = 0; k < 9; ++k) m2t[k] = 0.f;
        }

        // B[s][i] = sum_j m1[s,j] * m2[t,i,j]
        float B[24];
        #pragma unroll
        for (int s = 0; s < NR; ++s) {
            #pragma unroll
            for (int i = 0; i < 3; ++i) {
                B[s*3+i] = m1v[s*3+0] * m2t[i*3+0]
                         + m1v[s*3+1] * m2t[i*3+1]
                         + m1v[s*3+2] * m2t[i*3+2];
            }
        }

        // contr[r,s,t] -> LDS[p][tid]; p = r*(r+1)/2 + s (np.tril_indices order)
        #pragma unroll
        for (int r = 0; r < NR; ++r) {
            #pragma unroll
            for (int s = 0; s <= r; ++s) {
                const int p = r*(r+1)/2 + s;
                sbuf[p][tid] = m1v[r*3+0] * B[s*3+0]
                             + m1v[r*3+1] * B[s*3+1]
                             + m1v[r*3+2] * B[s*3+2];
            }
        }

        __syncthreads();

        // ---- cooperative writeout: 36 regions x 512 floats = 4608 float4 ----
        // sweep: f = sweep*512 + tid ; p = f/128 ; idx = f%128
        // lanes of a wave stay within one p -> 1 KB contiguous per wave-store.
        #pragma unroll
        for (int sweep = 0; sweep < 9; ++sweep) {
            const int f = sweep * BLK + tid;
            const int p = f >> 7;
            const int idx = f & 127;
            const long long g = block_base + 4 * idx;
            if (g + 3 < N_ATOMS) {
                float4 v = *reinterpret_cast<const float4*>(&sbuf[p][4 * idx]);
                *reinterpret_cast<float4*>(
                    out + (size_t)p * (NR * N_ATOMS) + (size_t)t * N_ATOMS + g) = v;
            }
        }
        __syncthreads();  // protect sbuf before next t-pass overwrites it
    }
}

extern "C" void kernel_launch(void* const* d_in, const int* in_sizes, int n_in,
                              void* d_out, int out_size, void* d_ws, size_t ws_size,
                              hipStream_t stream) {
    const float* m1 = (const float*)d_in[0];
    const float* m2 = (const float*)d_in[1];
    float* out = (float*)d_out;

    const int grid = (N_ATOMS + BLK - 1) / BLK;  // 489
    hipLaunchKernelGGL(moment_contr_kernel, dim3(grid), dim3(BLK), 0, stream,
                       m1, m2, out);
}

// Round 5
// 80.294 us; speedup vs baseline: 1.5195x; 1.3069x over previous
//
#include <hip/hip_runtime.h>

#define N_ATOMS 250000
#define NR 8
#define BLK 512          // threads per block == atoms per block
#define NP 36            // tril pairs
#define NBLK ((N_ATOMS + BLK - 1) / BLK)   // 489

typedef float f4 __attribute__((ext_vector_type(4)));
typedef float f4a4 __attribute__((ext_vector_type(4), aligned(4)));

// R4 skeleton + (a) NT writeout stores, (b) m2t(t+1) register prefetch,
// (c) bijective XCD-chunked block swizzle (m204: 489 % 8 != 0).
__global__ __launch_bounds__(BLK, 4) void moment_contr_kernel(
    const float* __restrict__ m1,   // [A, 8, 3]
    const float* __restrict__ m2,   // [A, 8, 3, 3]
    float* __restrict__ out)        // out[p*2000000 + t*250000 + a]
{
    __shared__ float sbuf[NP][BLK];  // 72 KB -> 2 blocks/CU

    // --- XCD-chunked swizzle: same-XCD blocks get consecutive atom chunks ---
    const int orig = blockIdx.x;
    const int q = NBLK / 8, r = NBLK % 8;      // 61, 1
    const int xcd = orig & 7;
    const int wgid = (xcd < r ? xcd * (q + 1)
                              : r * (q + 1) + (xcd - r) * q) + (orig >> 3);

    const int tid = threadIdx.x;
    const long long block_base = (long long)wgid * BLK;
    const long long a = block_base + tid;
    const bool live = (a < N_ATOMS);

    // ---- m1[a]: 24 floats, VGPR-resident for all 8 t-passes ----
    float m1v[24];
    if (live) {
        const f4* p = reinterpret_cast<const f4*>(m1 + (size_t)a * 24);
        #pragma unroll
        for (int k = 0; k < 6; ++k) {
            f4 v = p[k];
            m1v[4*k+0] = v.x; m1v[4*k+1] = v.y;
            m1v[4*k+2] = v.z; m1v[4*k+3] = v.w;
        }
    } else {
        #pragma unroll
        for (int k = 0; k < 24; ++k) m1v[k] = 0.f;
    }

    const float* m2a = m2 + (size_t)a * 72;

    // ---- prime the m2t pipeline (t = 0): 2x dwordx4 (4B-aligned) + 1 dword
    float m2t[9];
    if (live) {
        f4a4 v0 = *reinterpret_cast<const f4a4*>(m2a + 0);
        f4a4 v1 = *reinterpret_cast<const f4a4*>(m2a + 4);
        m2t[0]=v0.x; m2t[1]=v0.y; m2t[2]=v0.z; m2t[3]=v0.w;
        m2t[4]=v1.x; m2t[5]=v1.y; m2t[6]=v1.z; m2t[7]=v1.w;
        m2t[8]=m2a[8];
    } else {
        #pragma unroll
        for (int k = 0; k < 9; ++k) m2t[k] = 0.f;
    }

    for (int t = 0; t < NR; ++t) {
        // ---- prefetch m2[a, t+1] FIRST: latency hides under compute+writeout
        float m2n[9];
        if (t < NR - 1) {
            if (live) {
                const float* pn = m2a + (size_t)(t + 1) * 9;
                f4a4 v0 = *reinterpret_cast<const f4a4*>(pn + 0);
                f4a4 v1 = *reinterpret_cast<const f4a4*>(pn + 4);
                m2n[0]=v0.x; m2n[1]=v0.y; m2n[2]=v0.z; m2n[3]=v0.w;
                m2n[4]=v1.x; m2n[5]=v1.y; m2n[6]=v1.z; m2n[7]=v1.w;
                m2n[8]=pn[8];
            } else {
                #pragma unroll
                for (int k = 0; k < 9; ++k) m2n[k] = 0.f;
            }
        }

        // B[s][i] = sum_j m1[s,j] * m2[t,i,j]
        float B[24];
        #pragma unroll
        for (int s = 0; s < NR; ++s) {
            #pragma unroll
            for (int i = 0; i < 3; ++i) {
                B[s*3+i] = m1v[s*3+0] * m2t[i*3+0]
                         + m1v[s*3+1] * m2t[i*3+1]
                         + m1v[s*3+2] * m2t[i*3+2];
            }
        }

        // contr[r,s,t] -> LDS[p][tid]; p = r*(r+1)/2 + s (np.tril_indices order)
        #pragma unroll
        for (int rr = 0; rr < NR; ++rr) {
            #pragma unroll
            for (int s = 0; s <= rr; ++s) {
                const int p = rr*(rr+1)/2 + s;
                sbuf[p][tid] = m1v[rr*3+0] * B[s*3+0]
                             + m1v[rr*3+1] * B[s*3+1]
                             + m1v[rr*3+2] * B[s*3+2];
            }
        }

        __syncthreads();

        // ---- cooperative writeout: 36 regions x 512 floats, NT float4 ----
        // f = sweep*512 + tid; p = f/128; idx = f%128 -> 1 KB contiguous per
        // wave-store, 2 KB sequential run per (p,t) region per block.
        #pragma unroll
        for (int sweep = 0; sweep < 9; ++sweep) {
            const int f = sweep * BLK + tid;
            const int p = f >> 7;
            const int idx = f & 127;
            const long long g = block_base + 4 * idx;
            if (g + 3 < N_ATOMS) {
                f4 v = *reinterpret_cast<const f4*>(&sbuf[p][4 * idx]);
                __builtin_nontemporal_store(
                    v, reinterpret_cast<f4*>(
                        out + (size_t)p * (NR * N_ATOMS) + (size_t)t * N_ATOMS + g));
            }
        }
        __syncthreads();  // sbuf reuse guard

        #pragma unroll
        for (int k = 0; k < 9; ++k) m2t[k] = m2n[k];
    }
}

extern "C" void kernel_launch(void* const* d_in, const int* in_sizes, int n_in,
                              void* d_out, int out_size, void* d_ws, size_t ws_size,
                              hipStream_t stream) {
    const float* m1 = (const float*)d_in[0];
    const float* m2 = (const float*)d_in[1];
    float* out = (float*)d_out;

    hipLaunchKernelGGL(moment_contr_kernel, dim3(NBLK), dim3(BLK), 0, stream,
                       m1, m2, out);
}

// Round 6
// 76.799 us; speedup vs baseline: 1.5887x; 1.0455x over previous
//
#include <hip/hip_runtime.h>

#define N_ATOMS 250000
#define NR 8
#define BLK 512          // threads per block
#define NP 36            // tril pairs
#define NBLK ((N_ATOMS + BLK - 1) / BLK)   // 489

typedef float f4 __attribute__((ext_vector_type(4)));
typedef float f4a4 __attribute__((ext_vector_type(4), aligned(4)));

// R5 (NT stores + m2 prefetch + XCD swizzle) with BARRIER-FREE wave-private
// LDS staging: each wave owns sbuf[wid][36][64], synced by lgkmcnt only.
// Zero __syncthreads -> no vmcnt(0) drains, waves self-pipeline across t.
__global__ __launch_bounds__(BLK, 4) void moment_contr_kernel(
    const float* __restrict__ m1,   // [A, 8, 3]
    const float* __restrict__ m2,   // [A, 8, 3, 3]
    float* __restrict__ out)        // out[p*2000000 + t*250000 + a]
{
    __shared__ float sbuf[BLK / 64][NP][64];   // 8 x 9 KB = 72 KB

    // --- bijective XCD-chunked swizzle (489 % 8 != 0) ---
    const int orig = blockIdx.x;
    const int q = NBLK / 8, r = NBLK % 8;      // 61, 1
    const int xcd = orig & 7;
    const int wgid = (xcd < r ? xcd * (q + 1)
                              : r * (q + 1) + (xcd - r) * q) + (orig >> 3);

    const int tid  = threadIdx.x;
    const int wid  = tid >> 6;
    const int lane = tid & 63;
    const long long wbase = (long long)wgid * BLK + (long long)wid * 64;
    const long long a = wbase + lane;
    const bool live = (a < N_ATOMS);

    float (*swave)[64] = sbuf[wid];   // this wave's private slice

    // ---- m1[a]: 24 floats, VGPR-resident for all 8 t-passes ----
    float m1v[24];
    if (live) {
        const f4* p = reinterpret_cast<const f4*>(m1 + (size_t)a * 24);
        #pragma unroll
        for (int k = 0; k < 6; ++k) {
            f4 v = p[k];
            m1v[4*k+0] = v.x; m1v[4*k+1] = v.y;
            m1v[4*k+2] = v.z; m1v[4*k+3] = v.w;
        }
    } else {
        #pragma unroll
        for (int k = 0; k < 24; ++k) m1v[k] = 0.f;
    }

    const float* m2a = m2 + (size_t)a * 72;

    // ---- prime m2t (t = 0): 2x dwordx4 (4B-aligned) + 1 dword ----
    float m2t[9];
    if (live) {
        f4a4 v0 = *reinterpret_cast<const f4a4*>(m2a + 0);
        f4a4 v1 = *reinterpret_cast<const f4a4*>(m2a + 4);
        m2t[0]=v0.x; m2t[1]=v0.y; m2t[2]=v0.z; m2t[3]=v0.w;
        m2t[4]=v1.x; m2t[5]=v1.y; m2t[6]=v1.z; m2t[7]=v1.w;
        m2t[8]=m2a[8];
    } else {
        #pragma unroll
        for (int k = 0; k < 9; ++k) m2t[k] = 0.f;
    }

    for (int t = 0; t < NR; ++t) {
        // ---- prefetch m2[a, t+1]: latency hides under compute + writeout ----
        float m2n[9];
        if (t < NR - 1) {
            if (live) {
                const float* pn = m2a + (size_t)(t + 1) * 9;
                f4a4 v0 = *reinterpret_cast<const f4a4*>(pn + 0);
                f4a4 v1 = *reinterpret_cast<const f4a4*>(pn + 4);
                m2n[0]=v0.x; m2n[1]=v0.y; m2n[2]=v0.z; m2n[3]=v0.w;
                m2n[4]=v1.x; m2n[5]=v1.y; m2n[6]=v1.z; m2n[7]=v1.w;
                m2n[8]=pn[8];
            } else {
                #pragma unroll
                for (int k = 0; k < 9; ++k) m2n[k] = 0.f;
            }
        }

        // B[s][i] = sum_j m1[s,j] * m2[t,i,j]
        float B[24];
        #pragma unroll
        for (int s = 0; s < NR; ++s) {
            #pragma unroll
            for (int i = 0; i < 3; ++i) {
                B[s*3+i] = m1v[s*3+0] * m2t[i*3+0]
                         + m1v[s*3+1] * m2t[i*3+1]
                         + m1v[s*3+2] * m2t[i*3+2];
            }
        }

        // contr[r,s,t] -> wave-private LDS; p = r*(r+1)/2 + s (tril order).
        // stride-1 dword writes: 2 lanes/bank, conflict-free.
        #pragma unroll
        for (int rr = 0; rr < NR; ++rr) {
            #pragma unroll
            for (int s = 0; s <= rr; ++s) {
                const int p = rr*(rr+1)/2 + s;
                swave[p][lane] = m1v[rr*3+0] * B[s*3+0]
                               + m1v[rr*3+1] * B[s*3+1]
                               + m1v[rr*3+2] * B[s*3+2];
            }
        }

        // wave-internal visibility: drain LDS writes (no block barrier)
        asm volatile("s_waitcnt lgkmcnt(0)" ::: "memory");

        // ---- writeout: 36 regions x 64 floats = 9 dwordx4 per lane-wave ----
        // it-th instr: p = it*4 + lane/16, sub = (4*lane)%64 -> each 16-lane
        // group emits one contiguous 256 B segment; b128 read is 8-phase
        // minimum, conflict-free. N_ATOMS % 4 == 0 so f4 guard is exact.
        #pragma unroll
        for (int it = 0; it < 9; ++it) {
            const int p   = it * 4 + (lane >> 4);
            const int sub = (4 * lane) & 63;
            if (wbase + sub + 4 <= N_ATOMS) {
                f4 v = *reinterpret_cast<const f4*>(&swave[p][sub]);
                __builtin_nontemporal_store(
                    v, reinterpret_cast<f4*>(
                        out + (size_t)p * (NR * N_ATOMS) + (size_t)t * N_ATOMS
                            + wbase + sub));
            }
        }

        #pragma unroll
        for (int k = 0; k < 9; ++k) m2t[k] = m2n[k];
    }
}

extern "C" void kernel_launch(void* const* d_in, const int* in_sizes, int n_in,
                              void* d_out, int out_size, void* d_ws, size_t ws_size,
                              hipStream_t stream) {
    const float* m1 = (const float*)d_in[0];
    const float* m2 = (const float*)d_in[1];
    float* out = (float*)d_out;

    hipLaunchKernelGGL(moment_contr_kernel, dim3(NBLK), dim3(BLK), 0, stream,
                       m1, m2, out);
}

// Round 7
// 75.140 us; speedup vs baseline: 1.6237x; 1.0221x over previous
//
#include <hip/hip_runtime.h>

#define N_ATOMS 250000
#define NR 8
#define BLK 512          // threads per block
#define NP 36            // tril pairs
#define NBLK ((N_ATOMS + BLK - 1) / BLK)   // 489

typedef float f4 __attribute__((ext_vector_type(4)));

// R6 (wave-private LDS, no barriers, NT stores, XCD swizzle) with phase-
// separated reads: m2 loaded in 2 bursts of 36 floats, each feeding 4
// unrolled t-passes of pure compute+write (no loads interleaved).
__global__ __launch_bounds__(BLK, 4) void moment_contr_kernel(
    const float* __restrict__ m1,   // [A, 8, 3]
    const float* __restrict__ m2,   // [A, 8, 3, 3]
    float* __restrict__ out)        // out[p*2000000 + t*250000 + a]
{
    __shared__ float sbuf[BLK / 64][NP][64];   // 8 x 9 KB = 72 KB

    // --- bijective XCD-chunked swizzle (489 % 8 != 0) ---
    const int orig = blockIdx.x;
    const int q = NBLK / 8, r = NBLK % 8;      // 61, 1
    const int xcd = orig & 7;
    const int wgid = (xcd < r ? xcd * (q + 1)
                              : r * (q + 1) + (xcd - r) * q) + (orig >> 3);

    const int tid  = threadIdx.x;
    const int wid  = tid >> 6;
    const int lane = tid & 63;
    const long long wbase = (long long)wgid * BLK + (long long)wid * 64;
    const long long a = wbase + lane;
    const bool live = (a < N_ATOMS);

    float (*swave)[64] = sbuf[wid];   // this wave's private slice

    // ---- m1[a]: 24 floats, VGPR-resident throughout ----
    float m1v[24];
    if (live) {
        const f4* p = reinterpret_cast<const f4*>(m1 + (size_t)a * 24);
        #pragma unroll
        for (int k = 0; k < 6; ++k) {
            f4 v = p[k];
            m1v[4*k+0] = v.x; m1v[4*k+1] = v.y;
            m1v[4*k+2] = v.z; m1v[4*k+3] = v.w;
        }
    } else {
        #pragma unroll
        for (int k = 0; k < 24; ++k) m1v[k] = 0.f;
    }

    const float* m2a = m2 + (size_t)a * 72;   // 288 B/atom, 16B-aligned

    #pragma unroll
    for (int th = 0; th < 2; ++th) {
        // ---- burst-load half of m2: 36 floats = 9x dwordx4, 144 B/lane ----
        // (a*72 + th*36 floats = 288a + 144*th bytes: 16B-aligned)
        float m2h[36];
        if (live) {
            const f4* ph = reinterpret_cast<const f4*>(m2a + th * 36);
            #pragma unroll
            for (int k = 0; k < 9; ++k) {
                f4 v = ph[k];
                m2h[4*k+0] = v.x; m2h[4*k+1] = v.y;
                m2h[4*k+2] = v.z; m2h[4*k+3] = v.w;
            }
        } else {
            #pragma unroll
            for (int k = 0; k < 36; ++k) m2h[k] = 0.f;
        }

        // ---- 4 t-passes of pure compute + NT write (no loads) ----
        #pragma unroll
        for (int t4 = 0; t4 < 4; ++t4) {
            const int t = th * 4 + t4;

            // B[s][i] = sum_j m1[s,j] * m2[t,i,j]
            float B[24];
            #pragma unroll
            for (int s = 0; s < NR; ++s) {
                #pragma unroll
                for (int i = 0; i < 3; ++i) {
                    B[s*3+i] = m1v[s*3+0] * m2h[t4*9 + i*3 + 0]
                             + m1v[s*3+1] * m2h[t4*9 + i*3 + 1]
                             + m1v[s*3+2] * m2h[t4*9 + i*3 + 2];
                }
            }

            // contr[r,s,t] -> wave-private LDS; p = r*(r+1)/2 + s (tril order)
            #pragma unroll
            for (int rr = 0; rr < NR; ++rr) {
                #pragma unroll
                for (int s = 0; s <= rr; ++s) {
                    const int p = rr*(rr+1)/2 + s;
                    swave[p][lane] = m1v[rr*3+0] * B[s*3+0]
                                   + m1v[rr*3+1] * B[s*3+1]
                                   + m1v[rr*3+2] * B[s*3+2];
                }
            }

            // wave-internal visibility only (no block barrier)
            asm volatile("s_waitcnt lgkmcnt(0)" ::: "memory");

            // ---- writeout: 36 regions x 64 floats = 9 NT dwordx4/lane ----
            // p = it*4 + lane/16, sub = (4*lane)%64: each 16-lane group emits
            // one contiguous 256 B segment; b128 LDS read conflict-free.
            #pragma unroll
            for (int it = 0; it < 9; ++it) {
                const int p   = it * 4 + (lane >> 4);
                const int sub = (4 * lane) & 63;
                if (wbase + sub + 4 <= N_ATOMS) {
                    f4 v = *reinterpret_cast<const f4*>(&swave[p][sub]);
                    __builtin_nontemporal_store(
                        v, reinterpret_cast<f4*>(
                            out + (size_t)p * (NR * N_ATOMS)
                                + (size_t)t * N_ATOMS + wbase + sub));
                }
            }
        }
    }
}

extern "C" void kernel_launch(void* const* d_in, const int* in_sizes, int n_in,
                              void* d_out, int out_size, void* d_ws, size_t ws_size,
                              hipStream_t stream) {
    const float* m1 = (const float*)d_in[0];
    const float* m2 = (const float*)d_in[1];
    float* out = (float*)d_out;

    hipLaunchKernelGGL(moment_contr_kernel, dim3(NBLK), dim3(BLK), 0, stream,
                       m1, m2, out);
}